// Round 7
// baseline (387.463 us; speedup 1.0000x reference)
//
#include <hip/hip_runtime.h>

#define B_  4
#define L_  1024
#define D_  1024
#define NH_ 16
#define DH_ 64
#define H_  2730
#define HP3 3072
#define M_  4096  // B*L

typedef short bf16x8 __attribute__((ext_vector_type(8)));
typedef float f32x4  __attribute__((ext_vector_type(4)));

__device__ __forceinline__ unsigned short f2bf(float f) {
    unsigned int u = __builtin_bit_cast(unsigned int, f);
    u += 0x7fffu + ((u >> 16) & 1u);
    return (unsigned short)(u >> 16);
}
__device__ __forceinline__ float bf2f(unsigned short s) {
    unsigned int u = ((unsigned int)s) << 16;
    return __builtin_bit_cast(float, u);
}

__device__ __forceinline__ void glds16(const void* g, void* l) {
    __builtin_amdgcn_global_load_lds(
        (const __attribute__((address_space(1))) unsigned int*)g,
        (__attribute__((address_space(3))) unsigned int*)l, 16, 0, 0);
}

// bank swizzle: s = pos ^ ((row>>1)&3). For b128 frag reads (row stride 64B),
// the 16 lanes of a quad then hit every bank exactly 2x (the b128 floor; 2-way
// is free per m136). The old (row&3) gave 4-way on even rows (4.7M conflict cyc).
__device__ __forceinline__ int bswz(int row) { return (row >> 1) & 3; }

// stripe-XCD swizzle: same row-stripe (ly) -> same flat%8 -> same XCD L2 (A-reuse).
__device__ __forceinline__ void xcd_swz(int& lx, int& ly) {
    const int gx = gridDim.x;
    const int flat = blockIdx.x + gx * blockIdx.y;
    const int r = flat & 7, q = flat >> 3;
    lx = q % gx;
    ly = r + 8 * (q / gx);
}

// ---------------- weight fp32 [K][N] -> bf16 transposed [Np][Kp] (zero pad) ----------------
__global__ __launch_bounds__(256) void cvtT_kernel(
    const float* __restrict__ in, unsigned short* __restrict__ out,
    int K, int N, int Kp, int Np)
{
    __shared__ float t[32][33];
    const int k0 = blockIdx.x * 32, n0 = blockIdx.y * 32;
    const int tx = threadIdx.x & 31, ty = threadIdx.x >> 5;
    #pragma unroll
    for (int i = 0; i < 4; ++i) {
        const int k = k0 + ty + i * 8, n = n0 + tx;
        t[ty + i * 8][tx] = (k < K && n < N) ? in[(size_t)k * N + n] : 0.0f;
    }
    __syncthreads();
    #pragma unroll
    for (int i = 0; i < 4; ++i) {
        const int n = n0 + ty + i * 8, k = k0 + tx;
        out[(size_t)n * Kp + k] = f2bf(t[tx][ty + i * 8]);
    }
}

// ---------------- RMSNorm: fp32 in -> bf16 out ----------------
__global__ __launch_bounds__(256) void rmsnorm_kernel(
    const float* __restrict__ x, const float* __restrict__ w,
    unsigned short* __restrict__ out)
{
    const int row = blockIdx.x;
    const int t = threadIdx.x;
    const float4 v = ((const float4*)(x + (size_t)row * 1024))[t];
    float ss = v.x*v.x + v.y*v.y + v.z*v.z + v.w*v.w;
    #pragma unroll
    for (int off = 32; off > 0; off >>= 1) ss += __shfl_down(ss, off);
    __shared__ float red[4];
    if ((t & 63) == 0) red[t >> 6] = ss;
    __syncthreads();
    const float tot = red[0] + red[1] + red[2] + red[3];
    const float rr = rsqrtf(tot * (1.0f / 1024.0f) + 1e-8f);
    const float4 wv = ((const float4*)w)[t];
    ushort4 o;
    o.x = f2bf(v.x * wv.x * rr); o.y = f2bf(v.y * wv.y * rr);
    o.z = f2bf(v.z * wv.z * rr); o.w = f2bf(v.w * wv.w * rr);
    ((ushort4*)(out + (size_t)row * 1024))[t] = o;
}

// ---------------- bf16 MFMA GEMM, 128xTN tile, BK=32, S-stage glds pipeline ----------------
// EPI: 0 = out_bf16(acc + bias); 1 = out_f32(acc + bias + res); 4 = out_f32(acc + res)
template<int EPI, int TN, int S>
__global__ __launch_bounds__(256, 3) void gemm_bf16(
    const unsigned short* __restrict__ A, const unsigned short* __restrict__ Bt,
    int M, int N, int K,
    const float* __restrict__ bias, const float* __restrict__ res,
    float* __restrict__ outf, unsigned short* __restrict__ outb)
{
    constexpr int NS = TN / 32;
    constexpr int G  = (TN == 128) ? 4 : 3;
    constexpr int WAIT = 0xF70 | ((S - 1) * G);  // vmcnt((S-1)*G)
    __shared__ __align__(16) unsigned short As[S][128 * 32];
    __shared__ __align__(16) unsigned short Bs[S][TN * 32];
    const int tid = threadIdx.x;
    int lx, ly;
    xcd_swz(lx, ly);
    const int m0 = ly * 128, n0 = lx * TN;
    const int lane = tid & 63, w = tid >> 6;
    const int wm = w >> 1, wn = w & 1;
    const int quad = lane >> 4, l15 = lane & 15;

    f32x4 acc[4][NS] = {};

    const int p0 = w * 64 + lane;
    const int r0 = p0 >> 2, c0 = (p0 & 3) ^ bswz(r0);
    const int offL0 = p0 * 8, offL1 = 2048 + p0 * 8;

    const unsigned short* Ag0 = A + (size_t)(m0 + r0) * K + c0 * 8;
    const unsigned short* Ag1 = A + (size_t)(m0 + 64 + r0) * K + c0 * 8;
    const unsigned short* Bg0 = Bt + (size_t)(n0 + r0) * K + c0 * 8;
    const unsigned short* Bg1 = Bt + (size_t)(n0 + 64 + r0) * K + c0 * 8;

    auto stage = [&](int kk, int buf) {
        glds16(Ag0 + kk, &As[buf][offL0]);
        glds16(Ag1 + kk, &As[buf][offL1]);
        glds16(Bg0 + kk, &Bs[buf][offL0]);
        if (TN == 128) glds16(Bg1 + kk, &Bs[buf][offL1]);
    };
    auto compute = [&](int buf) {
        bf16x8 af[4], bfr[NS];
        #pragma unroll
        for (int ms = 0; ms < 4; ++ms) {
            const int row = wm * 64 + ms * 16 + l15;
            af[ms] = *(const bf16x8*)&As[buf][row * 32 + ((quad ^ bswz(row)) * 8)];
        }
        #pragma unroll
        for (int ns = 0; ns < NS; ++ns) {
            const int row = wn * (TN / 2) + ns * 16 + l15;
            bfr[ns] = *(const bf16x8*)&Bs[buf][row * 32 + ((quad ^ bswz(row)) * 8)];
        }
        #pragma unroll
        for (int ms = 0; ms < 4; ++ms)
            #pragma unroll
            for (int ns = 0; ns < NS; ++ns)
                acc[ms][ns] = __builtin_amdgcn_mfma_f32_16x16x32_bf16(
                    af[ms], bfr[ns], acc[ms][ns], 0, 0, 0);
    };

    const int nk = K >> 5;
    #pragma unroll
    for (int s = 0; s < S - 1; ++s) stage(s << 5, s);
    int cb = 0, sb = S - 1;
    for (int i = 0; i < nk; ++i) {
        if (i + S - 1 < nk) {
            stage((i + S - 1) << 5, sb);
            sb = (sb + 1 == S) ? 0 : sb + 1;
            __builtin_amdgcn_s_waitcnt(WAIT);
        } else {
            __builtin_amdgcn_s_waitcnt(0xF70);
        }
        __builtin_amdgcn_s_barrier();
        compute(cb);
        cb = (cb + 1 == S) ? 0 : cb + 1;
        __builtin_amdgcn_s_barrier();
    }

    #pragma unroll
    for (int ms = 0; ms < 4; ++ms) {
        #pragma unroll
        for (int r = 0; r < 4; ++r) {
            const int row = m0 + wm * 64 + ms * 16 + quad * 4 + r;
            const size_t ro = (size_t)row * N;
            #pragma unroll
            for (int ns = 0; ns < NS; ++ns) {
                const int col = n0 + wn * (TN / 2) + ns * 16 + l15;
                float v = acc[ms][ns][r];
                if (EPI == 0) {
                    outb[ro + col] = f2bf(v + bias[col]);
                } else if (EPI == 1) {
                    outf[ro + col] = v + bias[col] + res[ro + col];
                } else {
                    outf[ro + col] = v + res[ro + col];
                }
            }
        }
    }
}

// ---------------- fused SwiGLU GEMM: g = silu(A@U^T) * (A@V^T), 128x128, S=2, column-XCD ----------------
__global__ __launch_bounds__(256, 3) void gemm_swiglu(
    const unsigned short* __restrict__ A, const unsigned short* __restrict__ Bu,
    const unsigned short* __restrict__ Bv, unsigned short* __restrict__ g)
{
    constexpr int K = 1024, N = HP3, S = 2;
    constexpr int WAIT = 0xF70 | ((S - 1) * 6);  // vmcnt(6)
    __shared__ __align__(16) unsigned short As[S][128 * 32];
    __shared__ __align__(16) unsigned short Us[S][128 * 32];
    __shared__ __align__(16) unsigned short Vs[S][128 * 32];
    const int tid = threadIdx.x;
    // column-XCD grouping: each XCD owns 3 column-blocks (weights L2-resident);
    // within XCD, the 3 columns of a stripe are dispatched consecutively (A L2-hit).
    const int flat = blockIdx.x + 24 * blockIdx.y;
    const int rr = flat & 7, q = flat >> 3;       // q in 0..95
    const int lx = rr + 8 * (q % 3);              // 0..23
    const int ly = q / 3;                          // 0..31
    const int m0 = ly * 128, n0 = lx * 128;
    const int lane = tid & 63, w = tid >> 6;
    const int wm = w >> 1, wn = w & 1;
    const int quad = lane >> 4, l15 = lane & 15;

    f32x4 au[4][4] = {}, av[4][4] = {};

    const int p0 = w * 64 + lane;
    const int r0 = p0 >> 2, c0 = (p0 & 3) ^ bswz(r0);
    const int offL0 = p0 * 8, offL1 = 2048 + p0 * 8;

    const unsigned short* Ag0 = A  + (size_t)(m0 + r0) * K + c0 * 8;
    const unsigned short* Ag1 = A  + (size_t)(m0 + 64 + r0) * K + c0 * 8;
    const unsigned short* Ug0 = Bu + (size_t)(n0 + r0) * K + c0 * 8;
    const unsigned short* Ug1 = Bu + (size_t)(n0 + 64 + r0) * K + c0 * 8;
    const unsigned short* Vg0 = Bv + (size_t)(n0 + r0) * K + c0 * 8;
    const unsigned short* Vg1 = Bv + (size_t)(n0 + 64 + r0) * K + c0 * 8;

    auto stage = [&](int kk, int buf) {
        glds16(Ag0 + kk, &As[buf][offL0]);
        glds16(Ag1 + kk, &As[buf][offL1]);
        glds16(Ug0 + kk, &Us[buf][offL0]);
        glds16(Ug1 + kk, &Us[buf][offL1]);
        glds16(Vg0 + kk, &Vs[buf][offL0]);
        glds16(Vg1 + kk, &Vs[buf][offL1]);
    };
    auto compute = [&](int buf) {
        bf16x8 af[4], uf[4], vf[4];
        #pragma unroll
        for (int ms = 0; ms < 4; ++ms) {
            const int row = wm * 64 + ms * 16 + l15;
            af[ms] = *(const bf16x8*)&As[buf][row * 32 + ((quad ^ bswz(row)) * 8)];
        }
        #pragma unroll
        for (int ns = 0; ns < 4; ++ns) {
            const int row = wn * 64 + ns * 16 + l15;
            uf[ns] = *(const bf16x8*)&Us[buf][row * 32 + ((quad ^ bswz(row)) * 8)];
            vf[ns] = *(const bf16x8*)&Vs[buf][row * 32 + ((quad ^ bswz(row)) * 8)];
        }
        #pragma unroll
        for (int ms = 0; ms < 4; ++ms)
            #pragma unroll
            for (int ns = 0; ns < 4; ++ns) {
                au[ms][ns] = __builtin_amdgcn_mfma_f32_16x16x32_bf16(af[ms], uf[ns], au[ms][ns], 0, 0, 0);
                av[ms][ns] = __builtin_amdgcn_mfma_f32_16x16x32_bf16(af[ms], vf[ns], av[ms][ns], 0, 0, 0);
            }
    };

    constexpr int nk = K >> 5;  // 32
    #pragma unroll
    for (int s = 0; s < S - 1; ++s) stage(s << 5, s);
    int cb = 0, sb = S - 1;
    for (int i = 0; i < nk; ++i) {
        if (i + S - 1 < nk) {
            stage((i + S - 1) << 5, sb);
            sb = (sb + 1 == S) ? 0 : sb + 1;
            __builtin_amdgcn_s_waitcnt(WAIT);
        } else {
            __builtin_amdgcn_s_waitcnt(0xF70);
        }
        __builtin_amdgcn_s_barrier();
        compute(cb);
        cb = (cb + 1 == S) ? 0 : cb + 1;
        __builtin_amdgcn_s_barrier();
    }

    #pragma unroll
    for (int ms = 0; ms < 4; ++ms) {
        #pragma unroll
        for (int r = 0; r < 4; ++r) {
            const int row = m0 + wm * 64 + ms * 16 + quad * 4 + r;
            const size_t ro = (size_t)row * N;
            #pragma unroll
            for (int ns = 0; ns < 4; ++ns) {
                const int col = n0 + wn * 64 + ns * 16 + l15;
                const float uu = au[ms][ns][r];
                const float vv = av[ms][ns][r];
                g[ro + col] = f2bf(uu / (1.0f + __expf(-uu)) * vv);
            }
        }
    }
}

// ---------------- MFMA flash attention v2: pair-balanced, pipelined ----------------
__global__ __launch_bounds__(256) void attn_mfma2_kernel(
    const unsigned short* __restrict__ qkv, unsigned short* __restrict__ hout)
{
    __shared__ __align__(16) unsigned short Qs[2][64 * 72];
    __shared__ __align__(16) unsigned short Ks[2][64 * 64];
    __shared__ __align__(16) unsigned short Vt[2][64 * 72];
    __shared__ __align__(16) unsigned short Ps[64 * 68];

    const int tid = threadIdx.x;
    const int qa = blockIdx.x, h = blockIdx.y, b = blockIdx.z;
    const int qb = 15 - qa;
    const int w = tid >> 6, lane = tid & 63;
    const int quad = lane >> 4, l15 = lane & 15;

    const size_t basek = (size_t)(b * L_) * 3072 + 1024 + h * 64;
    const size_t basev = basek + 1024;

    {
        const int row = tid >> 1, half = tid & 1;
        const int tile = row >> 6, r6 = row & 63;
        const int grow = (tile ? qb : qa) * 64 + r6;
        const unsigned short* gp = qkv + (size_t)(b * L_ + grow) * 3072 + h * 64 + half * 32;
        uint4 a = *(const uint4*)gp;
        uint4 c = *(const uint4*)(gp + 8);
        uint4 d = *(const uint4*)(gp + 16);
        uint4 e = *(const uint4*)(gp + 24);
        unsigned short* dp = &Qs[tile][r6 * 72 + half * 32];
        *(uint4*)dp = a; *(uint4*)(dp + 8) = c; *(uint4*)(dp + 16) = d; *(uint4*)(dp + 24) = e;
    }

    auto stageK = [&](int kt, int buf) {
        #pragma unroll
        for (int i = 0; i < 2; ++i) {
            const int p = i * 256 + tid;
            const int row = p >> 3;
            const int cc = (p & 7) ^ (row & 7);
            glds16(qkv + basek + (size_t)(kt * 64 + row) * 3072 + cc * 8, &Ks[buf][p * 8]);
        }
    };
    const int vkey = (tid & 31) * 2, vdp = tid >> 5;
    auto loadV = [&](int kt, uint4& v0, uint4& v1) {
        const unsigned short* gp = qkv + basev + (size_t)(kt * 64 + vkey) * 3072 + vdp * 8;
        v0 = *(const uint4*)gp;
        v1 = *(const uint4*)(gp + 3072);
    };
    auto writeV = [&](int buf, const uint4& v0, const uint4& v1) {
        union { uint4 u; unsigned short s[8]; } a, c;
        a.u = v0; c.u = v1;
        #pragma unroll
        for (int i = 0; i < 8; ++i) {
            unsigned int pk = (unsigned int)a.s[i] | ((unsigned int)c.s[i] << 16);
            *(unsigned int*)&Vt[buf][(vdp * 8 + i) * 72 + vkey] = pk;
        }
    };

    f32x4 O[4] = {};
    float m4[4], l4[4];
    #pragma unroll
    for (int r = 0; r < 4; ++r) { m4[r] = -1e30f; l4[r] = 0.0f; }

    stageK(0, 0);
    {
        uint4 v0, v1;
        loadV(0, v0, v1);
        writeV(0, v0, v1);
    }
    __syncthreads();

    bf16x8 af[2];
    #pragma unroll
    for (int s = 0; s < 2; ++s)
        af[s] = *(const bf16x8*)&Qs[0][(w * 16 + l15) * 72 + s * 32 + quad * 8];

    int qsel = 0, kt = 0;
    for (int t = 0; t < 17; ++t) {
        const int cb = t & 1, nb = cb ^ 1;
        const bool havenext = (t < 16);
        uint4 nv0, nv1;
        if (havenext) {
            const int ktn = (t + 1 <= qa) ? (t + 1) : (t - qa);
            stageK(ktn, nb);
            loadV(ktn, nv0, nv1);
        }

        bf16x8 bfk[4][2];
        #pragma unroll
        for (int n = 0; n < 4; ++n) {
            const int row = n * 16 + l15;
            #pragma unroll
            for (int s = 0; s < 2; ++s)
                bfk[n][s] = *(const bf16x8*)&Ks[cb][row * 64 + (((s * 4 + quad) ^ (row & 7)) * 8)];
        }
        f32x4 sacc[4] = {};
        #pragma unroll
        for (int n = 0; n < 4; ++n) {
            sacc[n] = __builtin_amdgcn_mfma_f32_16x16x32_bf16(af[0], bfk[n][0], sacc[n], 0, 0, 0);
            sacc[n] = __builtin_amdgcn_mfma_f32_16x16x32_bf16(af[1], bfk[n][1], sacc[n], 0, 0, 0);
        }

        const bool diag = (kt == (qsel ? qb : qa));
        float p[4][4], mx[4];
        #pragma unroll
        for (int r = 0; r < 4; ++r) mx[r] = -1e30f;
        #pragma unroll
        for (int n = 0; n < 4; ++n) {
            const int col = n * 16 + l15;
            #pragma unroll
            for (int r = 0; r < 4; ++r) {
                float v = sacc[n][r] * 0.03125f;
                if (diag && col > (w * 16 + quad * 4 + r)) v = -1e30f;
                p[n][r] = v;
                mx[r] = fmaxf(mx[r], v);
            }
        }
        #pragma unroll
        for (int r = 0; r < 4; ++r) {
            #pragma unroll
            for (int m = 1; m < 16; m <<= 1)
                mx[r] = fmaxf(mx[r], __shfl_xor(mx[r], m));
        }
        float alpha[4], rs[4];
        #pragma unroll
        for (int r = 0; r < 4; ++r) {
            const float mnew = fmaxf(m4[r], mx[r]);
            alpha[r] = __expf(m4[r] - mnew);
            m4[r] = mnew;
            float s0 = 0.0f;
            #pragma unroll
            for (int n = 0; n < 4; ++n) {
                const float e = __expf(p[n][r] - mnew);
                p[n][r] = e;
                s0 += e;
            }
            rs[r] = s0;
        }
        #pragma unroll
        for (int r = 0; r < 4; ++r) {
            #pragma unroll
            for (int m = 1; m < 16; m <<= 1)
                rs[r] += __shfl_xor(rs[r], m);
            l4[r] = l4[r] * alpha[r] + rs[r];
        }
        #pragma unroll
        for (int dn = 0; dn < 4; ++dn)
            #pragma unroll
            for (int r = 0; r < 4; ++r)
                O[dn][r] *= alpha[r];
        #pragma unroll
        for (int n = 0; n < 4; ++n)
            #pragma unroll
            for (int r = 0; r < 4; ++r)
                Ps[(w * 16 + quad * 4 + r) * 68 + n * 16 + l15] = f2bf(p[n][r]);

        if (havenext) writeV(nb, nv0, nv1);

        bf16x8 ap[2], bv[4][2];
        #pragma unroll
        for (int s = 0; s < 2; ++s)
            ap[s] = *(const bf16x8*)&Ps[(w * 16 + l15) * 68 + s * 32 + quad * 8];
        #pragma unroll
        for (int dn = 0; dn < 4; ++dn)
            #pragma unroll
            for (int s = 0; s < 2; ++s)
                bv[dn][s] = *(const bf16x8*)&Vt[cb][(dn * 16 + l15) * 72 + s * 32 + quad * 8];
        #pragma unroll
        for (int dn = 0; dn < 4; ++dn) {
            O[dn] = __builtin_amdgcn_mfma_f32_16x16x32_bf16(ap[0], bv[dn][0], O[dn], 0, 0, 0);
            O[dn] = __builtin_amdgcn_mfma_f32_16x16x32_bf16(ap[1], bv[dn][1], O[dn], 0, 0, 0);
        }

        if (t == qa) {
            #pragma unroll
            for (int r = 0; r < 4; ++r) {
                const float inv = 1.0f / l4[r];
                const int grow = qa * 64 + w * 16 + quad * 4 + r;
                unsigned short* op = hout + (size_t)(b * L_ + grow) * 1024 + h * 64;
                #pragma unroll
                for (int dn = 0; dn < 4; ++dn)
                    op[dn * 16 + l15] = f2bf(O[dn][r] * inv);
            }
            #pragma unroll
            for (int dn = 0; dn < 4; ++dn)
                #pragma unroll
                for (int r = 0; r < 4; ++r) O[dn][r] = 0.0f;
            #pragma unroll
            for (int r = 0; r < 4; ++r) { m4[r] = -1e30f; l4[r] = 0.0f; }
            qsel = 1;
            kt = 0;
            #pragma unroll
            for (int s = 0; s < 2; ++s)
                af[s] = *(const bf16x8*)&Qs[1][(w * 16 + l15) * 72 + s * 32 + quad * 8];
        } else {
            ++kt;
        }
        __syncthreads();
    }

    #pragma unroll
    for (int r = 0; r < 4; ++r) {
        const float inv = 1.0f / l4[r];
        const int grow = qb * 64 + w * 16 + quad * 4 + r;
        unsigned short* op = hout + (size_t)(b * L_ + grow) * 1024 + h * 64;
        #pragma unroll
        for (int dn = 0; dn < 4; ++dn)
            op[dn * 16 + l15] = f2bf(O[dn][r] * inv);
    }
}

extern "C" void kernel_launch(void* const* d_in, const int* in_sizes, int n_in,
                              void* d_out, int out_size, void* d_ws, size_t ws_size,
                              hipStream_t stream)
{
    const float* x   = (const float*)d_in[0];
    const float* wx  = (const float*)d_in[2];
    const float* bx  = (const float*)d_in[3];
    const float* wo  = (const float*)d_in[4];
    const float* bo  = (const float*)d_in[5];
    const float* mhw = (const float*)d_in[6];
    const float* ffw = (const float*)d_in[7];
    const float* u   = (const float*)d_in[8];
    const float* v   = (const float*)d_in[9];
    const float* w   = (const float*)d_in[10];
    float* out = (float*)d_out;

    char* W = (char*)d_ws;
    unsigned short* xn_bf   = (unsigned short*)(W + 0);          //  8 MB [4096,1024]
    unsigned short* wx_bf   = (unsigned short*)(W + 8388608);    //  6 MB [3072,1024] (T)
    unsigned short* qkv_bf  = (unsigned short*)(W + 14680064);   // 24 MB [4096,3072]; reused as g
    unsigned short* head_bf = (unsigned short*)(W + 39845888);   //  8 MB [4096,1024]
    unsigned short* wo_bf   = (unsigned short*)(W + 48234496);   //  2 MB [1024,1024] (T)
    float*          x2      = (float*)(W + 50331648);            // 16 MB [4096,1024]
    unsigned short* u_bf    = (unsigned short*)(W + 67108864);   //  6 MB [3072,1024] (T)
    unsigned short* v_bf    = (unsigned short*)(W + 73400320);   //  6 MB [3072,1024] (T)
    unsigned short* w_bf    = (unsigned short*)(W + 79691776);   //  6 MB [1024,3072] (T)
    unsigned short* g_bf    = qkv_bf;                            // alias: qkv dead after attn

    cvtT_kernel<<<dim3(32, 96), 256, 0, stream>>>(wx, wx_bf, 1024, 3072, 1024, 3072);
    cvtT_kernel<<<dim3(32, 32), 256, 0, stream>>>(wo, wo_bf, 1024, 1024, 1024, 1024);
    cvtT_kernel<<<dim3(32, 96), 256, 0, stream>>>(u,  u_bf, 1024, 2730, 1024, 3072);
    cvtT_kernel<<<dim3(32, 96), 256, 0, stream>>>(v,  v_bf, 1024, 2730, 1024, 3072);
    cvtT_kernel<<<dim3(96, 32), 256, 0, stream>>>(w,  w_bf, 2730, 1024, 3072, 1024);

    rmsnorm_kernel<<<4096, 256, 0, stream>>>(x, mhw, xn_bf);

    gemm_bf16<0, 128, 3><<<dim3(24, 32), 256, 0, stream>>>(
        xn_bf, wx_bf, 4096, 3072, 1024, bx, nullptr, nullptr, qkv_bf);

    attn_mfma2_kernel<<<dim3(8, 16, 4), 256, 0, stream>>>(qkv_bf, head_bf);

    gemm_bf16<1, 64, 4><<<dim3(16, 32), 256, 0, stream>>>(
        head_bf, wo_bf, 4096, 1024, 1024, bo, x, x2, nullptr);

    rmsnorm_kernel<<<4096, 256, 0, stream>>>(x2, ffw, xn_bf);

    gemm_swiglu<<<dim3(24, 32), 256, 0, stream>>>(xn_bf, u_bf, v_bf, g_bf);

    gemm_bf16<4, 64, 4><<<dim3(16, 32), 256, 0, stream>>>(
        g_bf, w_bf, 4096, 1024, 3072, nullptr, x2, out, nullptr);
}

// Round 8
// 362.273 us; speedup vs baseline: 1.0695x; 1.0695x over previous
//
#include <hip/hip_runtime.h>

#define B_  4
#define L_  1024
#define D_  1024
#define NH_ 16
#define DH_ 64
#define H_  2730
#define HP3 3072
#define M_  4096  // B*L

typedef short bf16x8 __attribute__((ext_vector_type(8)));
typedef float f32x4  __attribute__((ext_vector_type(4)));

__device__ __forceinline__ unsigned short f2bf(float f) {
    unsigned int u = __builtin_bit_cast(unsigned int, f);
    u += 0x7fffu + ((u >> 16) & 1u);
    return (unsigned short)(u >> 16);
}
__device__ __forceinline__ float bf2f(unsigned short s) {
    unsigned int u = ((unsigned int)s) << 16;
    return __builtin_bit_cast(float, u);
}

__device__ __forceinline__ void glds16(const void* g, void* l) {
    __builtin_amdgcn_global_load_lds(
        (const __attribute__((address_space(1))) unsigned int*)g,
        (__attribute__((address_space(3))) unsigned int*)l, 16, 0, 0);
}

// bank swizzle: s = pos ^ ((row>>1)&3) -> b128 frag reads hit every bank exactly
// 2x (free per m136). Verified R7: SQ_LDS_BANK_CONFLICT 4.7M -> 0.
__device__ __forceinline__ int bswz(int row) { return (row >> 1) & 3; }

// stripe-XCD swizzle: same row-stripe (ly) -> same flat%8 -> same XCD L2 (A-reuse).
__device__ __forceinline__ void xcd_swz(int& lx, int& ly) {
    const int gx = gridDim.x;
    const int flat = blockIdx.x + gx * blockIdx.y;
    const int r = flat & 7, q = flat >> 3;
    lx = q % gx;
    ly = r + 8 * (q / gx);
}

// ---------------- weight fp32 [K][N] -> bf16 transposed [Np][Kp] (zero pad) ----------------
__global__ __launch_bounds__(256) void cvtT_kernel(
    const float* __restrict__ in, unsigned short* __restrict__ out,
    int K, int N, int Kp, int Np)
{
    __shared__ float t[32][33];
    const int k0 = blockIdx.x * 32, n0 = blockIdx.y * 32;
    const int tx = threadIdx.x & 31, ty = threadIdx.x >> 5;
    #pragma unroll
    for (int i = 0; i < 4; ++i) {
        const int k = k0 + ty + i * 8, n = n0 + tx;
        t[ty + i * 8][tx] = (k < K && n < N) ? in[(size_t)k * N + n] : 0.0f;
    }
    __syncthreads();
    #pragma unroll
    for (int i = 0; i < 4; ++i) {
        const int n = n0 + ty + i * 8, k = k0 + tx;
        out[(size_t)n * Kp + k] = f2bf(t[tx][ty + i * 8]);
    }
}

// ---------------- RMSNorm: fp32 in -> bf16 out ----------------
__global__ __launch_bounds__(256) void rmsnorm_kernel(
    const float* __restrict__ x, const float* __restrict__ w,
    unsigned short* __restrict__ out)
{
    const int row = blockIdx.x;
    const int t = threadIdx.x;
    const float4 v = ((const float4*)(x + (size_t)row * 1024))[t];
    float ss = v.x*v.x + v.y*v.y + v.z*v.z + v.w*v.w;
    #pragma unroll
    for (int off = 32; off > 0; off >>= 1) ss += __shfl_down(ss, off);
    __shared__ float red[4];
    if ((t & 63) == 0) red[t >> 6] = ss;
    __syncthreads();
    const float tot = red[0] + red[1] + red[2] + red[3];
    const float rr = rsqrtf(tot * (1.0f / 1024.0f) + 1e-8f);
    const float4 wv = ((const float4*)w)[t];
    ushort4 o;
    o.x = f2bf(v.x * wv.x * rr); o.y = f2bf(v.y * wv.y * rr);
    o.z = f2bf(v.z * wv.z * rr); o.w = f2bf(v.w * wv.w * rr);
    ((ushort4*)(out + (size_t)row * 1024))[t] = o;
}

// ---------------- bf16 MFMA GEMM, 128xTN tile, BK=32, S-stage glds pipeline ----------------
// EPI: 0 = out_bf16(acc + bias); 1 = out_f32(acc + bias + res); 4 = out_f32(acc + res)
template<int EPI, int TN, int S>
__global__ __launch_bounds__(256, 3) void gemm_bf16(
    const unsigned short* __restrict__ A, const unsigned short* __restrict__ Bt,
    int M, int N, int K,
    const float* __restrict__ bias, const float* __restrict__ res,
    float* __restrict__ outf, unsigned short* __restrict__ outb)
{
    constexpr int NS = TN / 32;
    constexpr int G  = (TN == 128) ? 4 : 3;
    constexpr int WAIT = 0xF70 | ((S - 1) * G);  // vmcnt((S-1)*G)
    __shared__ __align__(16) unsigned short As[S][128 * 32];
    __shared__ __align__(16) unsigned short Bs[S][TN * 32];
    const int tid = threadIdx.x;
    int lx, ly;
    xcd_swz(lx, ly);
    const int m0 = ly * 128, n0 = lx * TN;
    const int lane = tid & 63, w = tid >> 6;
    const int wm = w >> 1, wn = w & 1;
    const int quad = lane >> 4, l15 = lane & 15;

    f32x4 acc[4][NS] = {};

    const int p0 = w * 64 + lane;
    const int r0 = p0 >> 2, c0 = (p0 & 3) ^ bswz(r0);
    const int offL0 = p0 * 8, offL1 = 2048 + p0 * 8;

    const unsigned short* Ag0 = A + (size_t)(m0 + r0) * K + c0 * 8;
    const unsigned short* Ag1 = A + (size_t)(m0 + 64 + r0) * K + c0 * 8;
    const unsigned short* Bg0 = Bt + (size_t)(n0 + r0) * K + c0 * 8;
    const unsigned short* Bg1 = Bt + (size_t)(n0 + 64 + r0) * K + c0 * 8;

    auto stage = [&](int kk, int buf) {
        glds16(Ag0 + kk, &As[buf][offL0]);
        glds16(Ag1 + kk, &As[buf][offL1]);
        glds16(Bg0 + kk, &Bs[buf][offL0]);
        if (TN == 128) glds16(Bg1 + kk, &Bs[buf][offL1]);
    };
    auto compute = [&](int buf) {
        bf16x8 af[4], bfr[NS];
        #pragma unroll
        for (int ms = 0; ms < 4; ++ms) {
            const int row = wm * 64 + ms * 16 + l15;
            af[ms] = *(const bf16x8*)&As[buf][row * 32 + ((quad ^ bswz(row)) * 8)];
        }
        #pragma unroll
        for (int ns = 0; ns < NS; ++ns) {
            const int row = wn * (TN / 2) + ns * 16 + l15;
            bfr[ns] = *(const bf16x8*)&Bs[buf][row * 32 + ((quad ^ bswz(row)) * 8)];
        }
        #pragma unroll
        for (int ms = 0; ms < 4; ++ms)
            #pragma unroll
            for (int ns = 0; ns < NS; ++ns)
                acc[ms][ns] = __builtin_amdgcn_mfma_f32_16x16x32_bf16(
                    af[ms], bfr[ns], acc[ms][ns], 0, 0, 0);
    };

    const int nk = K >> 5;
    #pragma unroll
    for (int s = 0; s < S - 1; ++s) stage(s << 5, s);
    int cb = 0, sb = S - 1;
    for (int i = 0; i < nk; ++i) {
        if (i + S - 1 < nk) {
            stage((i + S - 1) << 5, sb);
            sb = (sb + 1 == S) ? 0 : sb + 1;
            __builtin_amdgcn_s_waitcnt(WAIT);
        } else {
            __builtin_amdgcn_s_waitcnt(0xF70);
        }
        __builtin_amdgcn_s_barrier();
        compute(cb);
        cb = (cb + 1 == S) ? 0 : cb + 1;
        __builtin_amdgcn_s_barrier();
    }

    #pragma unroll
    for (int ms = 0; ms < 4; ++ms) {
        #pragma unroll
        for (int r = 0; r < 4; ++r) {
            const int row = m0 + wm * 64 + ms * 16 + quad * 4 + r;
            const size_t ro = (size_t)row * N;
            #pragma unroll
            for (int ns = 0; ns < NS; ++ns) {
                const int col = n0 + wn * (TN / 2) + ns * 16 + l15;
                float v = acc[ms][ns][r];
                if (EPI == 0) {
                    outb[ro + col] = f2bf(v + bias[col]);
                } else if (EPI == 1) {
                    outf[ro + col] = v + bias[col] + res[ro + col];
                } else {
                    outf[ro + col] = v + res[ro + col];
                }
            }
        }
    }
}

// ---------------- fused SwiGLU GEMM: g = silu(A@U^T) * (A@V^T), 128x128, S=3, column-XCD ----------------
// S=3 + 2 blocks/CU: R6 vs R7 A/B showed 3 blocks/CU thrashes per-XCD L2
// (WRITE_SIZE doubled, MfmaUtil down). Keep 48-block/XCD residency.
__global__ __launch_bounds__(256, 2) void gemm_swiglu(
    const unsigned short* __restrict__ A, const unsigned short* __restrict__ Bu,
    const unsigned short* __restrict__ Bv, unsigned short* __restrict__ g)
{
    constexpr int K = 1024, N = HP3, S = 3;
    constexpr int WAIT = 0xF70 | ((S - 1) * 6);  // vmcnt(12)
    __shared__ __align__(16) unsigned short As[S][128 * 32];
    __shared__ __align__(16) unsigned short Us[S][128 * 32];
    __shared__ __align__(16) unsigned short Vs[S][128 * 32];
    const int tid = threadIdx.x;
    // column-XCD grouping: each XCD owns 3 column-blocks (weights L2-resident);
    // within XCD, the 3 columns of a stripe are dispatched consecutively (A L2-hit).
    const int flat = blockIdx.x + 24 * blockIdx.y;
    const int rr = flat & 7, q = flat >> 3;       // q in 0..95
    const int lx = rr + 8 * (q % 3);              // 0..23
    const int ly = q / 3;                          // 0..31
    const int m0 = ly * 128, n0 = lx * 128;
    const int lane = tid & 63, w = tid >> 6;
    const int wm = w >> 1, wn = w & 1;
    const int quad = lane >> 4, l15 = lane & 15;

    f32x4 au[4][4] = {}, av[4][4] = {};

    const int p0 = w * 64 + lane;
    const int r0 = p0 >> 2, c0 = (p0 & 3) ^ bswz(r0);
    const int offL0 = p0 * 8, offL1 = 2048 + p0 * 8;

    const unsigned short* Ag0 = A  + (size_t)(m0 + r0) * K + c0 * 8;
    const unsigned short* Ag1 = A  + (size_t)(m0 + 64 + r0) * K + c0 * 8;
    const unsigned short* Ug0 = Bu + (size_t)(n0 + r0) * K + c0 * 8;
    const unsigned short* Ug1 = Bu + (size_t)(n0 + 64 + r0) * K + c0 * 8;
    const unsigned short* Vg0 = Bv + (size_t)(n0 + r0) * K + c0 * 8;
    const unsigned short* Vg1 = Bv + (size_t)(n0 + 64 + r0) * K + c0 * 8;

    auto stage = [&](int kk, int buf) {
        glds16(Ag0 + kk, &As[buf][offL0]);
        glds16(Ag1 + kk, &As[buf][offL1]);
        glds16(Ug0 + kk, &Us[buf][offL0]);
        glds16(Ug1 + kk, &Us[buf][offL1]);
        glds16(Vg0 + kk, &Vs[buf][offL0]);
        glds16(Vg1 + kk, &Vs[buf][offL1]);
    };
    auto compute = [&](int buf) {
        bf16x8 af[4], uf[4], vf[4];
        #pragma unroll
        for (int ms = 0; ms < 4; ++ms) {
            const int row = wm * 64 + ms * 16 + l15;
            af[ms] = *(const bf16x8*)&As[buf][row * 32 + ((quad ^ bswz(row)) * 8)];
        }
        #pragma unroll
        for (int ns = 0; ns < 4; ++ns) {
            const int row = wn * 64 + ns * 16 + l15;
            uf[ns] = *(const bf16x8*)&Us[buf][row * 32 + ((quad ^ bswz(row)) * 8)];
            vf[ns] = *(const bf16x8*)&Vs[buf][row * 32 + ((quad ^ bswz(row)) * 8)];
        }
        #pragma unroll
        for (int ms = 0; ms < 4; ++ms)
            #pragma unroll
            for (int ns = 0; ns < 4; ++ns) {
                au[ms][ns] = __builtin_amdgcn_mfma_f32_16x16x32_bf16(af[ms], uf[ns], au[ms][ns], 0, 0, 0);
                av[ms][ns] = __builtin_amdgcn_mfma_f32_16x16x32_bf16(af[ms], vf[ns], av[ms][ns], 0, 0, 0);
            }
    };

    constexpr int nk = K >> 5;  // 32
    #pragma unroll
    for (int s = 0; s < S - 1; ++s) stage(s << 5, s);
    int cb = 0, sb = S - 1;
    for (int i = 0; i < nk; ++i) {
        if (i + S - 1 < nk) {
            stage((i + S - 1) << 5, sb);
            sb = (sb + 1 == S) ? 0 : sb + 1;
            __builtin_amdgcn_s_waitcnt(WAIT);
        } else {
            __builtin_amdgcn_s_waitcnt(0xF70);
        }
        __builtin_amdgcn_s_barrier();
        compute(cb);
        cb = (cb + 1 == S) ? 0 : cb + 1;
        __builtin_amdgcn_s_barrier();
    }

    #pragma unroll
    for (int ms = 0; ms < 4; ++ms) {
        #pragma unroll
        for (int r = 0; r < 4; ++r) {
            const int row = m0 + wm * 64 + ms * 16 + quad * 4 + r;
            const size_t ro = (size_t)row * N;
            #pragma unroll
            for (int ns = 0; ns < 4; ++ns) {
                const int col = n0 + wn * 64 + ns * 16 + l15;
                const float uu = au[ms][ns][r];
                const float vv = av[ms][ns][r];
                g[ro + col] = f2bf(uu / (1.0f + __expf(-uu)) * vv);
            }
        }
    }
}

// ---------------- MFMA flash attention v2: pair-balanced, pipelined ----------------
__global__ __launch_bounds__(256) void attn_mfma2_kernel(
    const unsigned short* __restrict__ qkv, unsigned short* __restrict__ hout)
{
    __shared__ __align__(16) unsigned short Qs[2][64 * 72];
    __shared__ __align__(16) unsigned short Ks[2][64 * 64];
    __shared__ __align__(16) unsigned short Vt[2][64 * 72];
    __shared__ __align__(16) unsigned short Ps[64 * 68];

    const int tid = threadIdx.x;
    const int qa = blockIdx.x, h = blockIdx.y, b = blockIdx.z;
    const int qb = 15 - qa;
    const int w = tid >> 6, lane = tid & 63;
    const int quad = lane >> 4, l15 = lane & 15;

    const size_t basek = (size_t)(b * L_) * 3072 + 1024 + h * 64;
    const size_t basev = basek + 1024;

    {
        const int row = tid >> 1, half = tid & 1;
        const int tile = row >> 6, r6 = row & 63;
        const int grow = (tile ? qb : qa) * 64 + r6;
        const unsigned short* gp = qkv + (size_t)(b * L_ + grow) * 3072 + h * 64 + half * 32;
        uint4 a = *(const uint4*)gp;
        uint4 c = *(const uint4*)(gp + 8);
        uint4 d = *(const uint4*)(gp + 16);
        uint4 e = *(const uint4*)(gp + 24);
        unsigned short* dp = &Qs[tile][r6 * 72 + half * 32];
        *(uint4*)dp = a; *(uint4*)(dp + 8) = c; *(uint4*)(dp + 16) = d; *(uint4*)(dp + 24) = e;
    }

    auto stageK = [&](int kt, int buf) {
        #pragma unroll
        for (int i = 0; i < 2; ++i) {
            const int p = i * 256 + tid;
            const int row = p >> 3;
            const int cc = (p & 7) ^ (row & 7);
            glds16(qkv + basek + (size_t)(kt * 64 + row) * 3072 + cc * 8, &Ks[buf][p * 8]);
        }
    };
    const int vkey = (tid & 31) * 2, vdp = tid >> 5;
    auto loadV = [&](int kt, uint4& v0, uint4& v1) {
        const unsigned short* gp = qkv + basev + (size_t)(kt * 64 + vkey) * 3072 + vdp * 8;
        v0 = *(const uint4*)gp;
        v1 = *(const uint4*)(gp + 3072);
    };
    auto writeV = [&](int buf, const uint4& v0, const uint4& v1) {
        union { uint4 u; unsigned short s[8]; } a, c;
        a.u = v0; c.u = v1;
        #pragma unroll
        for (int i = 0; i < 8; ++i) {
            unsigned int pk = (unsigned int)a.s[i] | ((unsigned int)c.s[i] << 16);
            *(unsigned int*)&Vt[buf][(vdp * 8 + i) * 72 + vkey] = pk;
        }
    };

    f32x4 O[4] = {};
    float m4[4], l4[4];
    #pragma unroll
    for (int r = 0; r < 4; ++r) { m4[r] = -1e30f; l4[r] = 0.0f; }

    stageK(0, 0);
    {
        uint4 v0, v1;
        loadV(0, v0, v1);
        writeV(0, v0, v1);
    }
    __syncthreads();

    bf16x8 af[2];
    #pragma unroll
    for (int s = 0; s < 2; ++s)
        af[s] = *(const bf16x8*)&Qs[0][(w * 16 + l15) * 72 + s * 32 + quad * 8];

    int qsel = 0, kt = 0;
    for (int t = 0; t < 17; ++t) {
        const int cb = t & 1, nb = cb ^ 1;
        const bool havenext = (t < 16);
        uint4 nv0, nv1;
        if (havenext) {
            const int ktn = (t + 1 <= qa) ? (t + 1) : (t - qa);
            stageK(ktn, nb);
            loadV(ktn, nv0, nv1);
        }

        bf16x8 bfk[4][2];
        #pragma unroll
        for (int n = 0; n < 4; ++n) {
            const int row = n * 16 + l15;
            #pragma unroll
            for (int s = 0; s < 2; ++s)
                bfk[n][s] = *(const bf16x8*)&Ks[cb][row * 64 + (((s * 4 + quad) ^ (row & 7)) * 8)];
        }
        f32x4 sacc[4] = {};
        #pragma unroll
        for (int n = 0; n < 4; ++n) {
            sacc[n] = __builtin_amdgcn_mfma_f32_16x16x32_bf16(af[0], bfk[n][0], sacc[n], 0, 0, 0);
            sacc[n] = __builtin_amdgcn_mfma_f32_16x16x32_bf16(af[1], bfk[n][1], sacc[n], 0, 0, 0);
        }

        const bool diag = (kt == (qsel ? qb : qa));
        float p[4][4], mx[4];
        #pragma unroll
        for (int r = 0; r < 4; ++r) mx[r] = -1e30f;
        #pragma unroll
        for (int n = 0; n < 4; ++n) {
            const int col = n * 16 + l15;
            #pragma unroll
            for (int r = 0; r < 4; ++r) {
                float v = sacc[n][r] * 0.03125f;
                if (diag && col > (w * 16 + quad * 4 + r)) v = -1e30f;
                p[n][r] = v;
                mx[r] = fmaxf(mx[r], v);
            }
        }
        #pragma unroll
        for (int r = 0; r < 4; ++r) {
            #pragma unroll
            for (int m = 1; m < 16; m <<= 1)
                mx[r] = fmaxf(mx[r], __shfl_xor(mx[r], m));
        }
        float alpha[4], rs[4];
        #pragma unroll
        for (int r = 0; r < 4; ++r) {
            const float mnew = fmaxf(m4[r], mx[r]);
            alpha[r] = __expf(m4[r] - mnew);
            m4[r] = mnew;
            float s0 = 0.0f;
            #pragma unroll
            for (int n = 0; n < 4; ++n) {
                const float e = __expf(p[n][r] - mnew);
                p[n][r] = e;
                s0 += e;
            }
            rs[r] = s0;
        }
        #pragma unroll
        for (int r = 0; r < 4; ++r) {
            #pragma unroll
            for (int m = 1; m < 16; m <<= 1)
                rs[r] += __shfl_xor(rs[r], m);
            l4[r] = l4[r] * alpha[r] + rs[r];
        }
        #pragma unroll
        for (int dn = 0; dn < 4; ++dn)
            #pragma unroll
            for (int r = 0; r < 4; ++r)
                O[dn][r] *= alpha[r];
        #pragma unroll
        for (int n = 0; n < 4; ++n)
            #pragma unroll
            for (int r = 0; r < 4; ++r)
                Ps[(w * 16 + quad * 4 + r) * 68 + n * 16 + l15] = f2bf(p[n][r]);

        if (havenext) writeV(nb, nv0, nv1);

        bf16x8 ap[2], bv[4][2];
        #pragma unroll
        for (int s = 0; s < 2; ++s)
            ap[s] = *(const bf16x8*)&Ps[(w * 16 + l15) * 68 + s * 32 + quad * 8];
        #pragma unroll
        for (int dn = 0; dn < 4; ++dn)
            #pragma unroll
            for (int s = 0; s < 2; ++s)
                bv[dn][s] = *(const bf16x8*)&Vt[cb][(dn * 16 + l15) * 72 + s * 32 + quad * 8];
        #pragma unroll
        for (int dn = 0; dn < 4; ++dn) {
            O[dn] = __builtin_amdgcn_mfma_f32_16x16x32_bf16(ap[0], bv[dn][0], O[dn], 0, 0, 0);
            O[dn] = __builtin_amdgcn_mfma_f32_16x16x32_bf16(ap[1], bv[dn][1], O[dn], 0, 0, 0);
        }

        if (t == qa) {
            #pragma unroll
            for (int r = 0; r < 4; ++r) {
                const float inv = 1.0f / l4[r];
                const int grow = qa * 64 + w * 16 + quad * 4 + r;
                unsigned short* op = hout + (size_t)(b * L_ + grow) * 1024 + h * 64;
                #pragma unroll
                for (int dn = 0; dn < 4; ++dn)
                    op[dn * 16 + l15] = f2bf(O[dn][r] * inv);
            }
            #pragma unroll
            for (int dn = 0; dn < 4; ++dn)
                #pragma unroll
                for (int r = 0; r < 4; ++r) O[dn][r] = 0.0f;
            #pragma unroll
            for (int r = 0; r < 4; ++r) { m4[r] = -1e30f; l4[r] = 0.0f; }
            qsel = 1;
            kt = 0;
            #pragma unroll
            for (int s = 0; s < 2; ++s)
                af[s] = *(const bf16x8*)&Qs[1][(w * 16 + l15) * 72 + s * 32 + quad * 8];
        } else {
            ++kt;
        }
        __syncthreads();
    }

    #pragma unroll
    for (int r = 0; r < 4; ++r) {
        const float inv = 1.0f / l4[r];
        const int grow = qb * 64 + w * 16 + quad * 4 + r;
        unsigned short* op = hout + (size_t)(b * L_ + grow) * 1024 + h * 64;
        #pragma unroll
        for (int dn = 0; dn < 4; ++dn)
            op[dn * 16 + l15] = f2bf(O[dn][r] * inv);
    }
}

extern "C" void kernel_launch(void* const* d_in, const int* in_sizes, int n_in,
                              void* d_out, int out_size, void* d_ws, size_t ws_size,
                              hipStream_t stream)
{
    const float* x   = (const float*)d_in[0];
    const float* wx  = (const float*)d_in[2];
    const float* bx  = (const float*)d_in[3];
    const float* wo  = (const float*)d_in[4];
    const float* bo  = (const float*)d_in[5];
    const float* mhw = (const float*)d_in[6];
    const float* ffw = (const float*)d_in[7];
    const float* u   = (const float*)d_in[8];
    const float* v   = (const float*)d_in[9];
    const float* w   = (const float*)d_in[10];
    float* out = (float*)d_out;

    char* W = (char*)d_ws;
    unsigned short* xn_bf   = (unsigned short*)(W + 0);          //  8 MB [4096,1024]
    unsigned short* wx_bf   = (unsigned short*)(W + 8388608);    //  6 MB [3072,1024] (T)
    unsigned short* qkv_bf  = (unsigned short*)(W + 14680064);   // 24 MB [4096,3072]; reused as g
    unsigned short* head_bf = (unsigned short*)(W + 39845888);   //  8 MB [4096,1024]
    unsigned short* wo_bf   = (unsigned short*)(W + 48234496);   //  2 MB [1024,1024] (T)
    float*          x2      = (float*)(W + 50331648);            // 16 MB [4096,1024]
    unsigned short* u_bf    = (unsigned short*)(W + 67108864);   //  6 MB [3072,1024] (T)
    unsigned short* v_bf    = (unsigned short*)(W + 73400320);   //  6 MB [3072,1024] (T)
    unsigned short* w_bf    = (unsigned short*)(W + 79691776);   //  6 MB [1024,3072] (T)
    unsigned short* g_bf    = qkv_bf;                            // alias: qkv dead after attn

    cvtT_kernel<<<dim3(32, 96), 256, 0, stream>>>(wx, wx_bf, 1024, 3072, 1024, 3072);
    cvtT_kernel<<<dim3(32, 32), 256, 0, stream>>>(wo, wo_bf, 1024, 1024, 1024, 1024);
    cvtT_kernel<<<dim3(32, 96), 256, 0, stream>>>(u,  u_bf, 1024, 2730, 1024, 3072);
    cvtT_kernel<<<dim3(32, 96), 256, 0, stream>>>(v,  v_bf, 1024, 2730, 1024, 3072);
    cvtT_kernel<<<dim3(96, 32), 256, 0, stream>>>(w,  w_bf, 2730, 1024, 3072, 1024);

    rmsnorm_kernel<<<4096, 256, 0, stream>>>(x, mhw, xn_bf);

    gemm_bf16<0, 128, 3><<<dim3(24, 32), 256, 0, stream>>>(
        xn_bf, wx_bf, 4096, 3072, 1024, bx, nullptr, nullptr, qkv_bf);

    attn_mfma2_kernel<<<dim3(8, 16, 4), 256, 0, stream>>>(qkv_bf, head_bf);

    gemm_bf16<1, 64, 4><<<dim3(16, 32), 256, 0, stream>>>(
        head_bf, wo_bf, 4096, 1024, 1024, bo, x, x2, nullptr);

    rmsnorm_kernel<<<4096, 256, 0, stream>>>(x2, ffw, xn_bf);

    gemm_swiglu<<<dim3(24, 32), 256, 0, stream>>>(xn_bf, u_bf, v_bf, g_bf);

    gemm_bf16<4, 64, 4><<<dim3(16, 32), 256, 0, stream>>>(
        g_bf, w_bf, 4096, 1024, 3072, nullptr, x2, out, nullptr);
}